// Round 14
// baseline (71.291 us; speedup 1.0000x reference)
//
#include <hip/hip_runtime.h>

// MultiHeadAttn: B=2, T=2048, D=1024, H=16, dh=64
// R14 = R11 configuration (best measured: 68.0us) + s_setprio(1) around attn
// MFMA clusters (T5: measured +4-7% on desync-wave attention, m191).
// Layouts: coalesced permuted per-head tiles; attn = 2 q-tiles/wave, split-2,
// no-barrier reg-direct loop, sched_barrier-pinned prefetch.

using short8   = __attribute__((ext_vector_type(8))) short;
using floatx4  = __attribute__((ext_vector_type(4))) float;
using floatx16 = __attribute__((ext_vector_type(16))) float;
using uintx4   = __attribute__((ext_vector_type(4))) unsigned int;
using ushort4v = __attribute__((ext_vector_type(4))) unsigned short;

__device__ __forceinline__ unsigned short f2bf(float f) {
    unsigned int u = __builtin_bit_cast(unsigned int, f);
    u += 0x7fffu + ((u >> 16) & 1u);
    return (unsigned short)(u >> 16);
}

// ---------------------------------------------------------------------------
// Kernel 0: fp32 -> bf16 convert of needed rows.
// ---------------------------------------------------------------------------
__global__ __launch_bounds__(256) void cvt_kernel(
    const float* __restrict__ Qs, const float* __restrict__ Ks,
    const float* __restrict__ Vs, const int* __restrict__ Qlen,
    const int* __restrict__ Vlen, unsigned short* __restrict__ abf)
{
    int z = blockIdx.y, row = blockIdx.x;
    int b = row >> 11, rib = row & 2047;
    int ql = Qlen[b]; int vl = Vlen[b]; int vle = vl ? vl : 2048;
    int lim = (z == 0) ? ((ql + 127) & ~127) : ((vle + 127) & ~127);
    if (rib >= lim) return;
    const float* src = (z == 0) ? Qs : ((z == 1) ? Ks : Vs);
    int t = threadIdx.x;
    float4 v = *reinterpret_cast<const float4*>(src + (size_t)row * 1024 + t * 4);
    ushort4v o;
    o[0] = f2bf(v.x); o[1] = f2bf(v.y); o[2] = f2bf(v.z); o[3] = f2bf(v.w);
    *reinterpret_cast<ushort4v*>(abf + (size_t)z * 4194304u + (size_t)row * 1024 + t * 4) = o;
}

// ---------------------------------------------------------------------------
// Kernel 1: W -> W^T bf16
// ---------------------------------------------------------------------------
__global__ __launch_bounds__(256) void wt_kernel(
    const float* __restrict__ W0, const float* __restrict__ W1,
    const float* __restrict__ W2, unsigned short* __restrict__ out)
{
    __shared__ float tile[64][65];
    int z = blockIdx.z;
    const float* W = (z == 0) ? W0 : ((z == 1) ? W1 : W2);
    unsigned short* O = out + (size_t)z * 1048576u;
    int r0 = blockIdx.y * 64, c0 = blockIdx.x * 64;
    int t = threadIdx.x;
#pragma unroll
    for (int i = 0; i < 16; i++) {
        int idx = t + i * 256; int r = idx >> 6, c = idx & 63;
        tile[r][c] = W[(size_t)(r0 + r) * 1024 + c0 + c];
    }
    __syncthreads();
#pragma unroll
    for (int i = 0; i < 16; i++) {
        int idx = t + i * 256; int c = idx >> 6, r = idx & 63;
        O[(size_t)(c0 + c) * 1024 + r0 + r] = f2bf(tile[r][c]);
    }
}

// ---------------------------------------------------------------------------
// Kernel 2: projection GEMM (PRECVT); permuted per-head tile epilogue.
// ---------------------------------------------------------------------------
__global__ __launch_bounds__(256) void proj_kernel(
    const unsigned short* __restrict__ abf, const unsigned short* __restrict__ wt,
    const int* __restrict__ Qlen, const int* __restrict__ Vlen,
    unsigned short* __restrict__ q, unsigned short* __restrict__ k,
    unsigned short* __restrict__ vh)
{
    __shared__ alignas(16) unsigned short As[128][72];
    __shared__ alignas(16) unsigned short Bs[128][72];

    int z = blockIdx.z;
    int tid = threadIdx.x;
    int m0 = blockIdx.y * 128, n0 = blockIdx.x * 128;
    int b = m0 >> 11, rib = m0 & 2047;
    int ql = Qlen[b]; int vl = Vlen[b]; int vle = vl ? vl : 2048;
    int lim = (z == 0) ? ((ql + 127) & ~127) : ((vle + 127) & ~127);
    if (rib >= lim) return;

    const unsigned short* Ab = abf + (size_t)z * 4194304u;
    const unsigned short* Bt = wt + (size_t)z * 1048576u;

    int w = tid >> 6, lane = tid & 63, g = lane >> 4, lr = lane & 15;
    int wr = w >> 1, wc = w & 1;

    floatx4 acc[4][4];
#pragma unroll
    for (int m = 0; m < 4; m++)
#pragma unroll
        for (int n = 0; n < 4; n++) {
#pragma unroll
            for (int r = 0; r < 4; r++) acc[m][n][r] = 0.f;
        }

    int srow = tid >> 1, scol = (tid & 1) * 32;

    short8 pa[4], pb[4];
#pragma unroll
    for (int i = 0; i < 4; i++) {
        pa[i] = *reinterpret_cast<const short8*>(Ab + (size_t)(m0 + srow) * 1024 + scol + i * 8);
        pb[i] = *reinterpret_cast<const short8*>(Bt + (size_t)(n0 + srow) * 1024 + scol + i * 8);
    }

    for (int kb = 0; kb < 1024; kb += 64) {
        __syncthreads();
#pragma unroll
        for (int i = 0; i < 4; i++) {
            *reinterpret_cast<short8*>(&As[srow][scol + i * 8]) = pa[i];
            *reinterpret_cast<short8*>(&Bs[srow][scol + i * 8]) = pb[i];
        }
        __syncthreads();

        if (kb + 64 < 1024) {
#pragma unroll
            for (int i = 0; i < 4; i++) {
                pa[i] = *reinterpret_cast<const short8*>(Ab + (size_t)(m0 + srow) * 1024 + kb + 64 + scol + i * 8);
                pb[i] = *reinterpret_cast<const short8*>(Bt + (size_t)(n0 + srow) * 1024 + kb + 64 + scol + i * 8);
            }
        }

#pragma unroll
        for (int kc = 0; kc < 2; kc++) {
            short8 af[4], bf[4];
#pragma unroll
            for (int m = 0; m < 4; m++)
                af[m] = *reinterpret_cast<const short8*>(&As[wr * 64 + m * 16 + lr][kc * 32 + g * 8]);
#pragma unroll
            for (int n = 0; n < 4; n++)
                bf[n] = *reinterpret_cast<const short8*>(&Bs[wc * 64 + n * 16 + lr][kc * 32 + g * 8]);
#pragma unroll
            for (int m = 0; m < 4; m++)
#pragma unroll
                for (int n = 0; n < 4; n++)
                    acc[m][n] = __builtin_amdgcn_mfma_f32_16x16x32_bf16(af[m], bf[n], acc[m][n], 0, 0, 0);
        }
    }

    if (z < 2) {
        unsigned short* outp = (z == 0) ? q : k;
#pragma unroll
        for (int m = 0; m < 4; m++) {
            int row0 = m0 + wr * 64 + m * 16 + g * 4;
            int tb = row0 & 2047;
            int tile = tb >> 6, rin = tb & 63;
#pragma unroll
            for (int n = 0; n < 4; n++) {
                int col = n0 + wc * 64 + n * 16 + lr;
                int hh = col >> 6, dd = col & 63;
                int cc = dd >> 4, h2 = (dd >> 3) & 1, u = dd & 7;
                size_t base = ((size_t)(b * 16 + hh) * 32 + tile) * 4096
                            + (size_t)((cc * 2 + h2) * 512) + (size_t)rin * 8 + u;
#pragma unroll
                for (int r = 0; r < 4; r++)
                    outp[base + (size_t)r * 8] = f2bf(acc[m][n][r]);
            }
        }
    } else {
#pragma unroll
        for (int m = 0; m < 4; m++) {
            int row0 = m0 + wr * 64 + m * 16 + g * 4;
            int tg = row0 & 2047;
            int tile = tg >> 6, kin = tg & 63;
            int cc = kin >> 4, h2 = (kin >> 3) & 1, u = kin & 7;
#pragma unroll
            for (int n = 0; n < 4; n++) {
                int col = n0 + wc * 64 + n * 16 + lr;
                int hh = col >> 6, dd = col & 63;
                ushort4v pk;
#pragma unroll
                for (int r = 0; r < 4; r++) pk[r] = f2bf(acc[m][n][r]);
                size_t addr = ((size_t)(b * 16 + hh) * 32 + tile) * 4096
                            + (size_t)((cc * 2 + h2) * 512) + (size_t)dd * 8 + u;
                *reinterpret_cast<ushort4v*>(vh + addr) = pk;
            }
        }
    }
}

// ---------------------------------------------------------------------------
// Kernel 3: flash attention (R11 structure + setprio around MFMA clusters).
// ---------------------------------------------------------------------------
__global__ __launch_bounds__(128) void attn_kernel(
    const unsigned short* __restrict__ q, const unsigned short* __restrict__ k,
    const unsigned short* __restrict__ vh, const int* __restrict__ Qlen,
    const int* __restrict__ Vlen, float* __restrict__ out)
{
    __shared__ float obuf[2][64][33];
    __shared__ float mlm[2][2][33];
    __shared__ float mll[2][2][33];

    int tid = threadIdx.x;
    int w = tid >> 6, lane = tid & 63;
    int j = lane & 31, hi = lane >> 5;

    int blk = blockIdx.x;
    int x = blk & 7, idx = blk >> 3;
    int bh = x + 8 * (idx >> 5), qb = idx & 31;
    int b = bh >> 4, h = bh & 15;
    int qlen = Qlen[b]; int vl = Vlen[b]; int vle = vl ? vl : 2048;

    if (qb * 64 >= qlen) {
        int zr = qb * 64 + (tid >> 1);
        float* p = out + (size_t)(b * 2048 + zr) * 1024 + h * 64 + (tid & 1) * 32;
        float4 z4; z4.x = 0.f; z4.y = 0.f; z4.z = 0.f; z4.w = 0.f;
#pragma unroll
        for (int s = 0; s < 8; s++) *reinterpret_cast<float4*>(p + 4 * s) = z4;
        return;
    }

    int nt = (vle + 63) >> 6;
    int ntw = (nt - w + 1) >> 1;

    size_t hb = (size_t)(b * 16 + h) * 131072u;
    const unsigned short* kh = k + hb;
    const unsigned short* vb = vh + hb;
    int lo = hi * 512 + j * 8;

    short8 qfA[4], qfB[4];
    {
        const unsigned short* qt = q + hb + (size_t)qb * 4096 + lo;
#pragma unroll
        for (int c = 0; c < 4; c++) {
            qfA[c] = *reinterpret_cast<const short8*>(qt + c * 1024);
            qfB[c] = *reinterpret_cast<const short8*>(qt + c * 1024 + 256);
        }
    }

    short8 kf0[4], kf1[4], vf0[4], vf1[4];
    {
        int t0 = (w < nt) ? w : (nt - 1);
        const unsigned short* kt0 = kh + (size_t)t0 * 4096 + lo;
        const unsigned short* vt0 = vb + (size_t)t0 * 4096 + lo;
#pragma unroll
        for (int c = 0; c < 4; c++) {
            kf0[c] = *reinterpret_cast<const short8*>(kt0 + c * 1024);
            kf1[c] = *reinterpret_cast<const short8*>(kt0 + c * 1024 + 256);
            vf0[c] = *reinterpret_cast<const short8*>(vt0 + c * 1024);
            vf1[c] = *reinterpret_cast<const short8*>(vt0 + c * 1024 + 256);
        }
    }
    __builtin_amdgcn_sched_barrier(0);

    floatx16 OA0, OA1, OB0, OB1;
#pragma unroll
    for (int t = 0; t < 16; t++) { OA0[t] = 0.f; OA1[t] = 0.f; OB0[t] = 0.f; OB1[t] = 0.f; }
    float mA = -3.0e38f, lA = 0.f, mB = -3.0e38f, lB = 0.f;

    const float CEXP = 0.18033688011112042f;

    for (int mi = 0; mi < ntw; ++mi) {
        int tix = w + 2 * mi;
        int kt = tix << 6;
        int tnx = tix + 2; if (tnx >= nt) tnx = nt - 1;

        // ================= Q-TILE A =================
        floatx16 s0, s1;
#pragma unroll
        for (int t = 0; t < 16; t++) { s0[t] = 0.f; s1[t] = 0.f; }
        __builtin_amdgcn_s_setprio(1);
#pragma unroll
        for (int c = 0; c < 4; c++) {
            s0 = __builtin_amdgcn_mfma_f32_32x32x16_bf16(kf0[c], qfA[c], s0, 0, 0, 0);
            s1 = __builtin_amdgcn_mfma_f32_32x32x16_bf16(kf1[c], qfA[c], s1, 0, 0, 0);
        }
        __builtin_amdgcn_s_setprio(0);
        if (kt + 64 > vle) {
#pragma unroll
            for (int t = 0; t < 16; t++) {
                int kl = (t & 3) + 8 * (t >> 2) + 4 * hi;
                if (kt + kl >= vle)      s0[t] = -8.0e12f;
                if (kt + 32 + kl >= vle) s1[t] = -8.0e12f;
            }
        }
        {   // softmax A
            float mx = s0[0];
#pragma unroll
            for (int t = 1; t < 16; t++) mx = fmaxf(mx, s0[t]);
#pragma unroll
            for (int t = 0; t < 16; t++) mx = fmaxf(mx, s1[t]);
            float lm = fmaxf(mx, __shfl_xor(mx, 32));
            if (__any(lm > mA + 64.f)) {
                float mn = fmaxf(mA, lm);
                float al = __builtin_amdgcn_exp2f((mA - mn) * CEXP);
                mA = mn; lA *= al;
#pragma unroll
                for (int t = 0; t < 16; t++) { OA0[t] *= al; OA1[t] *= al; }
            }
            float nm = -mA * CEXP;
#pragma unroll
            for (int t = 0; t < 16; t++) {
                s0[t] = __builtin_amdgcn_exp2f(fmaf(s0[t], CEXP, nm));
                s1[t] = __builtin_amdgcn_exp2f(fmaf(s1[t], CEXP, nm));
            }
            float rs = 0.f;
#pragma unroll
            for (int t = 0; t < 16; t++) rs += s0[t] + s1[t];
            lA += rs;
        }
        {   // pack A + PV A
            unsigned int pbw[4][4];
            unsigned int D[4][2];
#pragma unroll
            for (int s = 0; s < 4; s++) {
                asm("v_cvt_pk_bf16_f32 %0, %1, %2" : "=v"(D[s][0]) : "v"(s0[4*s+0]), "v"(s0[4*s+1]));
                asm("v_cvt_pk_bf16_f32 %0, %1, %2" : "=v"(D[s][1]) : "v"(s0[4*s+2]), "v"(s0[4*s+3]));
            }
#pragma unroll
            for (int u = 0; u < 2; u++) {
                asm volatile("v_permlane32_swap_b32 %0, %1" : "+v"(D[0][u]), "+v"(D[1][u]));
                asm volatile("v_permlane32_swap_b32 %0, %1" : "+v"(D[2][u]), "+v"(D[3][u]));
                pbw[0][u] = D[0][u]; pbw[0][u + 2] = D[1][u];
                pbw[1][u] = D[2][u]; pbw[1][u + 2] = D[3][u];
            }
#pragma unroll
            for (int s = 0; s < 4; s++) {
                asm("v_cvt_pk_bf16_f32 %0, %1, %2" : "=v"(D[s][0]) : "v"(s1[4*s+0]), "v"(s1[4*s+1]));
                asm("v_cvt_pk_bf16_f32 %0, %1, %2" : "=v"(D[s][1]) : "v"(s1[4*s+2]), "v"(s1[4*s+3]));
            }
#pragma unroll
            for (int u = 0; u < 2; u++) {
                asm volatile("v_permlane32_swap_b32 %0, %1" : "+v"(D[0][u]), "+v"(D[1][u]));
                asm volatile("v_permlane32_swap_b32 %0, %1" : "+v"(D[2][u]), "+v"(D[3][u]));
                pbw[2][u] = D[0][u]; pbw[2][u + 2] = D[1][u];
                pbw[3][u] = D[2][u]; pbw[3][u + 2] = D[3][u];
            }
            __builtin_amdgcn_s_setprio(1);
#pragma unroll
            for (int c = 0; c < 4; c++) {
                uintx4 pw; pw[0] = pbw[c][0]; pw[1] = pbw[c][1]; pw[2] = pbw[c][2]; pw[3] = pbw[c][3];
                short8 pf = __builtin_bit_cast(short8, pw);
                OA0 = __builtin_amdgcn_mfma_f32_32x32x16_bf16(vf0[c], pf, OA0, 0, 0, 0);
                OA1 = __builtin_amdgcn_mfma_f32_32x32x16_bf16(vf1[c], pf, OA1, 0, 0, 0);
            }
            __builtin_amdgcn_s_setprio(0);
        }

        // ================= Q-TILE B =================
#pragma unroll
        for (int t = 0; t < 16; t++) { s0[t] = 0.f; s1[t] = 0.f; }
        __builtin_amdgcn_s_setprio(1);
#pragma unroll
        for (int c = 0; c < 4; c++) {
            s0 = __builtin_amdgcn_mfma_f32_32x32x16_bf16(kf0[c], qfB[c], s0, 0, 0, 0);
            s1 = __builtin_amdgcn_mfma_f32_32x32x16_bf16(kf1[c], qfB[c], s1, 0, 0, 0);
        }
        __builtin_amdgcn_s_setprio(0);
        {
            const unsigned short* kn = kh + (size_t)tnx * 4096 + lo;
#pragma unroll
            for (int c = 0; c < 4; c++) {
                kf0[c] = *reinterpret_cast<const short8*>(kn + c * 1024);
                kf1[c] = *reinterpret_cast<const short8*>(kn + c * 1024 + 256);
            }
        }
        __builtin_amdgcn_sched_barrier(0);

        if (kt + 64 > vle) {
#pragma unroll
            for (int t = 0; t < 16; t++) {
                int kl = (t & 3) + 8 * (t >> 2) + 4 * hi;
                if (kt + kl >= vle)      s0[t] = -8.0e12f;
                if (kt + 32 + kl >= vle) s1[t] = -8.0e12f;
            }
        }
        {   // softmax B
            float mx = s0[0];
#pragma unroll
            for (int t = 1; t < 16; t++) mx = fmaxf(mx, s0[t]);
#pragma unroll
            for (int t = 0; t < 16; t++) mx = fmaxf(mx, s1[t]);
            float lm = fmaxf(mx, __shfl_xor(mx, 32));
            if (__any(lm > mB + 64.f)) {
                float mn = fmaxf(mB, lm);
                float al = __builtin_amdgcn_exp2f((mB - mn) * CEXP);
                mB = mn; lB *= al;
#pragma unroll
                for (int t = 0; t < 16; t++) { OB0[t] *= al; OB1[t] *= al; }
            }
            float nm = -mB * CEXP;
#pragma unroll
            for (int t = 0; t < 16; t++) {
                s0[t] = __builtin_amdgcn_exp2f(fmaf(s0[t], CEXP, nm));
                s1[t] = __builtin_amdgcn_exp2f(fmaf(s1[t], CEXP, nm));
            }
            float rs = 0.f;
#pragma unroll
            for (int t = 0; t < 16; t++) rs += s0[t] + s1[t];
            lB += rs;
        }
        {   // pack B + PV B
            unsigned int pbw[4][4];
            unsigned int D[4][2];
#pragma unroll
            for (int s = 0; s < 4; s++) {
                asm("v_cvt_pk_bf16_f32 %0, %1, %2" : "=v"(D[s][0]) : "v"(s0[4*s+0]), "v"(s0[4*s+1]));
                asm("v_cvt_pk_bf16_f32 %0, %1, %2" : "=v"(D[s][1]) : "v"(s0[4*s+2]), "v"(s0[4*s+3]));
            }
#pragma unroll
            for (int u = 0; u < 2; u++) {
                asm volatile("v_permlane32_swap_b32 %0, %1" : "+v"(D[0][u]), "+v"(D[1][u]));
                asm volatile("v_permlane32_swap_b32 %0, %1" : "+v"(D[2][u]), "+v"(D[3][u]));
                pbw[0][u] = D[0][u]; pbw[0][u + 2] = D[1][u];
                pbw[1][u] = D[2][u]; pbw[1][u + 2] = D[3][u];
            }
#pragma unroll
            for (int s = 0; s < 4; s++) {
                asm("v_cvt_pk_bf16_f32 %0, %1, %2" : "=v"(D[s][0]) : "v"(s1[4*s+0]), "v"(s1[4*s+1]));
                asm("v_cvt_pk_bf16_f32 %0, %1, %2" : "=v"(D[s][1]) : "v"(s1[4*s+2]), "v"(s1[4*s+3]));
            }
#pragma unroll
            for (int u = 0; u < 2; u++) {
                asm volatile("v_permlane32_swap_b32 %0, %1" : "+v"(D[0][u]), "+v"(D[1][u]));
                asm volatile("v_permlane32_swap_b32 %0, %1" : "+v"(D[2][u]), "+v"(D[3][u]));
                pbw[2][u] = D[0][u]; pbw[2][u + 2] = D[1][u];
                pbw[3][u] = D[2][u]; pbw[3][u + 2] = D[3][u];
            }
            __builtin_amdgcn_s_setprio(1);
#pragma unroll
            for (int c = 0; c < 4; c++) {
                uintx4 pw; pw[0] = pbw[c][0]; pw[1] = pbw[c][1]; pw[2] = pbw[c][2]; pw[3] = pbw[c][3];
                short8 pf = __builtin_bit_cast(short8, pw);
                OB0 = __builtin_amdgcn_mfma_f32_32x32x16_bf16(vf0[c], pf, OB0, 0, 0, 0);
                OB1 = __builtin_amdgcn_mfma_f32_32x32x16_bf16(vf1[c], pf, OB1, 0, 0, 0);
            }
            __builtin_amdgcn_s_setprio(0);
        }
        {
            const unsigned short* vn = vb + (size_t)tnx * 4096 + lo;
#pragma unroll
            for (int c = 0; c < 4; c++) {
                vf0[c] = *reinterpret_cast<const short8*>(vn + c * 1024);
                vf1[c] = *reinterpret_cast<const short8*>(vn + c * 1024 + 256);
            }
        }
        __builtin_amdgcn_sched_barrier(0);
    }

    // ================= combine (2 waves x 2 qtiles) ========================
    lA = lA + __shfl_xor(lA, 32);
    lB = lB + __shfl_xor(lB, 32);
    if (hi == 0) { mlm[0][w][j] = mA; mlm[1][w][j] = mB; }
    __syncthreads();
    float MA = fmaxf(mlm[0][0][j], mlm[0][1][j]);
    float MB = fmaxf(mlm[1][0][j], mlm[1][1][j]);
    float alA = __builtin_amdgcn_exp2f((mA - MA) * CEXP);
    float alB = __builtin_amdgcn_exp2f((mB - MB) * CEXP);
#pragma unroll
    for (int t = 0; t < 16; t++) { OA0[t] *= alA; OA1[t] *= alA; OB0[t] *= alB; OB1[t] *= alB; }
    if (hi == 0) { mll[0][w][j] = lA * alA; mll[1][w][j] = lB * alB; }
    if (w == 1) {
#pragma unroll
        for (int t = 0; t < 16; t++) {
            obuf[0][lane][t]      = OA0[t];
            obuf[0][lane][t + 16] = OA1[t];
            obuf[1][lane][t]      = OB0[t];
            obuf[1][lane][t + 16] = OB1[t];
        }
    }
    __syncthreads();
    if (w == 0) {
#pragma unroll
        for (int t = 0; t < 16; t++) {
            OA0[t] += obuf[0][lane][t];
            OA1[t] += obuf[0][lane][t + 16];
            OB0[t] += obuf[1][lane][t];
            OB1[t] += obuf[1][lane][t + 16];
        }
        float ltA = mll[0][0][j] + mll[0][1][j];
        float ltB = mll[1][0][j] + mll[1][1][j];
        int qrA = qb * 64 + j, qrB = qb * 64 + 32 + j;
        float qmA = (qrA < qlen) ? (1.0f / ltA) : 0.f;
        float qmB = (qrB < qlen) ? (1.0f / ltB) : 0.f;
        float* oa = out + (size_t)(b * 2048 + qrA) * 1024 + h * 64;
        float* ob = out + (size_t)(b * 2048 + qrB) * 1024 + h * 64;
#pragma unroll
        for (int s = 0; s < 4; s++) {
            float4 v0, v1;
            v0.x = OA0[4*s+0] * qmA; v0.y = OA0[4*s+1] * qmA; v0.z = OA0[4*s+2] * qmA; v0.w = OA0[4*s+3] * qmA;
            v1.x = OA1[4*s+0] * qmA; v1.y = OA1[4*s+1] * qmA; v1.z = OA1[4*s+2] * qmA; v1.w = OA1[4*s+3] * qmA;
            *reinterpret_cast<float4*>(oa + 8 * s + 4 * hi) = v0;
            *reinterpret_cast<float4*>(oa + 32 + 8 * s + 4 * hi) = v1;
            v0.x = OB0[4*s+0] * qmB; v0.y = OB0[4*s+1] * qmB; v0.z = OB0[4*s+2] * qmB; v0.w = OB0[4*s+3] * qmB;
            v1.x = OB1[4*s+0] * qmB; v1.y = OB1[4*s+1] * qmB; v1.z = OB1[4*s+2] * qmB; v1.w = OB1[4*s+3] * qmB;
            *reinterpret_cast<float4*>(ob + 8 * s + 4 * hi) = v0;
            *reinterpret_cast<float4*>(ob + 32 + 8 * s + 4 * hi) = v1;
        }
    }
}

// ---------------------------------------------------------------------------
extern "C" void kernel_launch(void* const* d_in, const int* in_sizes, int n_in,
                              void* d_out, int out_size, void* d_ws, size_t ws_size,
                              hipStream_t stream)
{
    const float* Q_seq = (const float*)d_in[0];
    const float* K_seq = (const float*)d_in[1];
    const float* V_seq = (const float*)d_in[2];
    const int*   Q_len = (const int*)d_in[3];
    const int*   V_len = (const int*)d_in[4];
    const float* WQ    = (const float*)d_in[5];
    const float* WK    = (const float*)d_in[6];
    const float* WV    = (const float*)d_in[7];
    float* outp = (float*)d_out;

    // ws layout (bf16 elems): wt[3*1M] | qh[4M] | kh[4M] | vh[4M] | abf[3*4M]
    unsigned short* wsb = (unsigned short*)d_ws;
    unsigned short* wt  = wsb;
    unsigned short* qp  = wsb + (size_t)3 * 1048576u;
    unsigned short* kp  = qp + 4194304u;
    unsigned short* vhp = kp + 4194304u;
    unsigned short* abf = vhp + 4194304u;

    wt_kernel<<<dim3(16, 16, 3), 256, 0, stream>>>(WQ, WK, WV, wt);
    cvt_kernel<<<dim3(4096, 3), 256, 0, stream>>>(Q_seq, K_seq, V_seq, Q_len, V_len, abf);
    proj_kernel<<<dim3(8, 32, 3), 256, 0, stream>>>(abf, wt, Q_len, V_len, qp, kp, vhp);
    attn_kernel<<<dim3(1024), 128, 0, stream>>>(qp, kp, vhp, Q_len, V_len, outp);
}

// Round 15
// 69.514 us; speedup vs baseline: 1.0256x; 1.0256x over previous
//
#include <hip/hip_runtime.h>

// MultiHeadAttn: B=2, T=2048, D=1024, H=16, dh=64
// R15 = R11 exact (best measured: 68.0us total, attn 40.2us).
// Pipeline: wt (W->W^T bf16) | cvt (fp32->bf16 rows, keeps proj A-reads
// L3-resident — R12 proved removing it costs +32us) | proj GEMM (PRECVT,
// permuted per-head tile epilogue) | attn (coalesced fragment loads,
// 2 q-tiles/wave, split-2, no-barrier reg-direct loop, pinned prefetch).
// R12-R14 probes: tree-softmax neutral, setprio neutral-negative -> omitted.

using short8   = __attribute__((ext_vector_type(8))) short;
using floatx4  = __attribute__((ext_vector_type(4))) float;
using floatx16 = __attribute__((ext_vector_type(16))) float;
using uintx4   = __attribute__((ext_vector_type(4))) unsigned int;
using ushort4v = __attribute__((ext_vector_type(4))) unsigned short;

__device__ __forceinline__ unsigned short f2bf(float f) {
    unsigned int u = __builtin_bit_cast(unsigned int, f);
    u += 0x7fffu + ((u >> 16) & 1u);
    return (unsigned short)(u >> 16);
}

// ---------------------------------------------------------------------------
// Kernel 0: fp32 -> bf16 convert of needed rows.
// ---------------------------------------------------------------------------
__global__ __launch_bounds__(256) void cvt_kernel(
    const float* __restrict__ Qs, const float* __restrict__ Ks,
    const float* __restrict__ Vs, const int* __restrict__ Qlen,
    const int* __restrict__ Vlen, unsigned short* __restrict__ abf)
{
    int z = blockIdx.y, row = blockIdx.x;
    int b = row >> 11, rib = row & 2047;
    int ql = Qlen[b]; int vl = Vlen[b]; int vle = vl ? vl : 2048;
    int lim = (z == 0) ? ((ql + 127) & ~127) : ((vle + 127) & ~127);
    if (rib >= lim) return;
    const float* src = (z == 0) ? Qs : ((z == 1) ? Ks : Vs);
    int t = threadIdx.x;
    float4 v = *reinterpret_cast<const float4*>(src + (size_t)row * 1024 + t * 4);
    ushort4v o;
    o[0] = f2bf(v.x); o[1] = f2bf(v.y); o[2] = f2bf(v.z); o[3] = f2bf(v.w);
    *reinterpret_cast<ushort4v*>(abf + (size_t)z * 4194304u + (size_t)row * 1024 + t * 4) = o;
}

// ---------------------------------------------------------------------------
// Kernel 1: W [1024][1024] f32 -> W^T [1024][1024] bf16 (z = 0,1,2)
// ---------------------------------------------------------------------------
__global__ __launch_bounds__(256) void wt_kernel(
    const float* __restrict__ W0, const float* __restrict__ W1,
    const float* __restrict__ W2, unsigned short* __restrict__ out)
{
    __shared__ float tile[64][65];
    int z = blockIdx.z;
    const float* W = (z == 0) ? W0 : ((z == 1) ? W1 : W2);
    unsigned short* O = out + (size_t)z * 1048576u;
    int r0 = blockIdx.y * 64, c0 = blockIdx.x * 64;
    int t = threadIdx.x;
#pragma unroll
    for (int i = 0; i < 16; i++) {
        int idx = t + i * 256; int r = idx >> 6, c = idx & 63;
        tile[r][c] = W[(size_t)(r0 + r) * 1024 + c0 + c];
    }
    __syncthreads();
#pragma unroll
    for (int i = 0; i < 16; i++) {
        int idx = t + i * 256; int c = idx >> 6, r = idx & 63;
        O[(size_t)(c0 + c) * 1024 + r0 + r] = f2bf(tile[r][c]);
    }
}

// ---------------------------------------------------------------------------
// Kernel 2: projection GEMM (PRECVT); permuted per-head tile epilogue.
// Layout per (b,h), per 64-row tile, element (row, d):
//   off = ((d>>4)*2 + ((d>>3)&1))*512 + row*8 + (d&7)     [K, Q]
// V per tile, element (d, key):
//   off = ((key>>4)*2 + ((key>>3)&1))*512 + d*8 + (key&7)
// ---------------------------------------------------------------------------
__global__ __launch_bounds__(256) void proj_kernel(
    const unsigned short* __restrict__ abf, const unsigned short* __restrict__ wt,
    const int* __restrict__ Qlen, const int* __restrict__ Vlen,
    unsigned short* __restrict__ q, unsigned short* __restrict__ k,
    unsigned short* __restrict__ vh)
{
    __shared__ alignas(16) unsigned short As[128][72];
    __shared__ alignas(16) unsigned short Bs[128][72];

    int z = blockIdx.z;
    int tid = threadIdx.x;
    int m0 = blockIdx.y * 128, n0 = blockIdx.x * 128;
    int b = m0 >> 11, rib = m0 & 2047;
    int ql = Qlen[b]; int vl = Vlen[b]; int vle = vl ? vl : 2048;
    int lim = (z == 0) ? ((ql + 127) & ~127) : ((vle + 127) & ~127);
    if (rib >= lim) return;

    const unsigned short* Ab = abf + (size_t)z * 4194304u;
    const unsigned short* Bt = wt + (size_t)z * 1048576u;

    int w = tid >> 6, lane = tid & 63, g = lane >> 4, lr = lane & 15;
    int wr = w >> 1, wc = w & 1;

    floatx4 acc[4][4];
#pragma unroll
    for (int m = 0; m < 4; m++)
#pragma unroll
        for (int n = 0; n < 4; n++) {
#pragma unroll
            for (int r = 0; r < 4; r++) acc[m][n][r] = 0.f;
        }

    int srow = tid >> 1, scol = (tid & 1) * 32;

    short8 pa[4], pb[4];
#pragma unroll
    for (int i = 0; i < 4; i++) {
        pa[i] = *reinterpret_cast<const short8*>(Ab + (size_t)(m0 + srow) * 1024 + scol + i * 8);
        pb[i] = *reinterpret_cast<const short8*>(Bt + (size_t)(n0 + srow) * 1024 + scol + i * 8);
    }

    for (int kb = 0; kb < 1024; kb += 64) {
        __syncthreads();
#pragma unroll
        for (int i = 0; i < 4; i++) {
            *reinterpret_cast<short8*>(&As[srow][scol + i * 8]) = pa[i];
            *reinterpret_cast<short8*>(&Bs[srow][scol + i * 8]) = pb[i];
        }
        __syncthreads();

        if (kb + 64 < 1024) {
#pragma unroll
            for (int i = 0; i < 4; i++) {
                pa[i] = *reinterpret_cast<const short8*>(Ab + (size_t)(m0 + srow) * 1024 + kb + 64 + scol + i * 8);
                pb[i] = *reinterpret_cast<const short8*>(Bt + (size_t)(n0 + srow) * 1024 + kb + 64 + scol + i * 8);
            }
        }

#pragma unroll
        for (int kc = 0; kc < 2; kc++) {
            short8 af[4], bf[4];
#pragma unroll
            for (int m = 0; m < 4; m++)
                af[m] = *reinterpret_cast<const short8*>(&As[wr * 64 + m * 16 + lr][kc * 32 + g * 8]);
#pragma unroll
            for (int n = 0; n < 4; n++)
                bf[n] = *reinterpret_cast<const short8*>(&Bs[wc * 64 + n * 16 + lr][kc * 32 + g * 8]);
#pragma unroll
            for (int m = 0; m < 4; m++)
#pragma unroll
                for (int n = 0; n < 4; n++)
                    acc[m][n] = __builtin_amdgcn_mfma_f32_16x16x32_bf16(af[m], bf[n], acc[m][n], 0, 0, 0);
        }
    }

    if (z < 2) {
        unsigned short* outp = (z == 0) ? q : k;
#pragma unroll
        for (int m = 0; m < 4; m++) {
            int row0 = m0 + wr * 64 + m * 16 + g * 4;
            int tb = row0 & 2047;
            int tile = tb >> 6, rin = tb & 63;
#pragma unroll
            for (int n = 0; n < 4; n++) {
                int col = n0 + wc * 64 + n * 16 + lr;
                int hh = col >> 6, dd = col & 63;
                int cc = dd >> 4, h2 = (dd >> 3) & 1, u = dd & 7;
                size_t base = ((size_t)(b * 16 + hh) * 32 + tile) * 4096
                            + (size_t)((cc * 2 + h2) * 512) + (size_t)rin * 8 + u;
#pragma unroll
                for (int r = 0; r < 4; r++)
                    outp[base + (size_t)r * 8] = f2bf(acc[m][n][r]);
            }
        }
    } else {
#pragma unroll
        for (int m = 0; m < 4; m++) {
            int row0 = m0 + wr * 64 + m * 16 + g * 4;
            int tg = row0 & 2047;
            int tile = tg >> 6, kin = tg & 63;
            int cc = kin >> 4, h2 = (kin >> 3) & 1, u = kin & 7;
#pragma unroll
            for (int n = 0; n < 4; n++) {
                int col = n0 + wc * 64 + n * 16 + lr;
                int hh = col >> 6, dd = col & 63;
                ushort4v pk;
#pragma unroll
                for (int r = 0; r < 4; r++) pk[r] = f2bf(acc[m][n][r]);
                size_t addr = ((size_t)(b * 16 + hh) * 32 + tile) * 4096
                            + (size_t)((cc * 2 + h2) * 512) + (size_t)dd * 8 + u;
                *reinterpret_cast<ushort4v*>(vh + addr) = pk;
            }
        }
    }
}

// ---------------------------------------------------------------------------
// Kernel 3: flash attention (R11). 128 thr = 2 waves; block = 64 q rows
// (2 q-tiles A,B per wave); split-2 over KV tiles; no-barrier reg-direct
// loop with coalesced fragment loads (base + c*1024B + lane*16B); pinned
// prefetch; combine at end. Grid 1024 (XCD-balanced).
// ---------------------------------------------------------------------------
__global__ __launch_bounds__(128) void attn_kernel(
    const unsigned short* __restrict__ q, const unsigned short* __restrict__ k,
    const unsigned short* __restrict__ vh, const int* __restrict__ Qlen,
    const int* __restrict__ Vlen, float* __restrict__ out)
{
    __shared__ float obuf[2][64][33];
    __shared__ float mlm[2][2][33];
    __shared__ float mll[2][2][33];

    int tid = threadIdx.x;
    int w = tid >> 6, lane = tid & 63;
    int j = lane & 31, hi = lane >> 5;

    int blk = blockIdx.x;
    int x = blk & 7, idx = blk >> 3;
    int bh = x + 8 * (idx >> 5), qb = idx & 31;
    int b = bh >> 4, h = bh & 15;
    int qlen = Qlen[b]; int vl = Vlen[b]; int vle = vl ? vl : 2048;

    if (qb * 64 >= qlen) {   // dead block -> zeros
        int zr = qb * 64 + (tid >> 1);
        float* p = out + (size_t)(b * 2048 + zr) * 1024 + h * 64 + (tid & 1) * 32;
        float4 z4; z4.x = 0.f; z4.y = 0.f; z4.z = 0.f; z4.w = 0.f;
#pragma unroll
        for (int s = 0; s < 8; s++) *reinterpret_cast<float4*>(p + 4 * s) = z4;
        return;
    }

    int nt = (vle + 63) >> 6;
    int ntw = (nt - w + 1) >> 1;

    size_t hb = (size_t)(b * 16 + h) * 131072u;
    const unsigned short* kh = k + hb;
    const unsigned short* vb = vh + hb;
    int lo = hi * 512 + j * 8;

    short8 qfA[4], qfB[4];
    {
        const unsigned short* qt = q + hb + (size_t)qb * 4096 + lo;
#pragma unroll
        for (int c = 0; c < 4; c++) {
            qfA[c] = *reinterpret_cast<const short8*>(qt + c * 1024);
            qfB[c] = *reinterpret_cast<const short8*>(qt + c * 1024 + 256);
        }
    }

    short8 kf0[4], kf1[4], vf0[4], vf1[4];
    {
        int t0 = (w < nt) ? w : (nt - 1);
        const unsigned short* kt0 = kh + (size_t)t0 * 4096 + lo;
        const unsigned short* vt0 = vb + (size_t)t0 * 4096 + lo;
#pragma unroll
        for (int c = 0; c < 4; c++) {
            kf0[c] = *reinterpret_cast<const short8*>(kt0 + c * 1024);
            kf1[c] = *reinterpret_cast<const short8*>(kt0 + c * 1024 + 256);
            vf0[c] = *reinterpret_cast<const short8*>(vt0 + c * 1024);
            vf1[c] = *reinterpret_cast<const short8*>(vt0 + c * 1024 + 256);
        }
    }
    __builtin_amdgcn_sched_barrier(0);

    floatx16 OA0, OA1, OB0, OB1;
#pragma unroll
    for (int t = 0; t < 16; t++) { OA0[t] = 0.f; OA1[t] = 0.f; OB0[t] = 0.f; OB1[t] = 0.f; }
    float mA = -3.0e38f, lA = 0.f, mB = -3.0e38f, lB = 0.f;

    const float CEXP = 0.18033688011112042f;

    for (int mi = 0; mi < ntw; ++mi) {
        int tix = w + 2 * mi;
        int kt = tix << 6;
        int tnx = tix + 2; if (tnx >= nt) tnx = nt - 1;

        // ================= Q-TILE A =================
        floatx16 s0, s1;
#pragma unroll
        for (int t = 0; t < 16; t++) { s0[t] = 0.f; s1[t] = 0.f; }
#pragma unroll
        for (int c = 0; c < 4; c++) {
            s0 = __builtin_amdgcn_mfma_f32_32x32x16_bf16(kf0[c], qfA[c], s0, 0, 0, 0);
            s1 = __builtin_amdgcn_mfma_f32_32x32x16_bf16(kf1[c], qfA[c], s1, 0, 0, 0);
        }
        if (kt + 64 > vle) {
#pragma unroll
            for (int t = 0; t < 16; t++) {
                int kl = (t & 3) + 8 * (t >> 2) + 4 * hi;
                if (kt + kl >= vle)      s0[t] = -8.0e12f;
                if (kt + 32 + kl >= vle) s1[t] = -8.0e12f;
            }
        }
        {   // softmax A
            float mx = s0[0];
#pragma unroll
            for (int t = 1; t < 16; t++) mx = fmaxf(mx, s0[t]);
#pragma unroll
            for (int t = 0; t < 16; t++) mx = fmaxf(mx, s1[t]);
            float lm = fmaxf(mx, __shfl_xor(mx, 32));
            if (__any(lm > mA + 64.f)) {
                float mn = fmaxf(mA, lm);
                float al = __builtin_amdgcn_exp2f((mA - mn) * CEXP);
                mA = mn; lA *= al;
#pragma unroll
                for (int t = 0; t < 16; t++) { OA0[t] *= al; OA1[t] *= al; }
            }
            float nm = -mA * CEXP;
#pragma unroll
            for (int t = 0; t < 16; t++) {
                s0[t] = __builtin_amdgcn_exp2f(fmaf(s0[t], CEXP, nm));
                s1[t] = __builtin_amdgcn_exp2f(fmaf(s1[t], CEXP, nm));
            }
            float rs = 0.f;
#pragma unroll
            for (int t = 0; t < 16; t++) rs += s0[t] + s1[t];
            lA += rs;
        }
        {   // pack A + PV A
            unsigned int pbw[4][4];
            unsigned int D[4][2];
#pragma unroll
            for (int s = 0; s < 4; s++) {
                asm("v_cvt_pk_bf16_f32 %0, %1, %2" : "=v"(D[s][0]) : "v"(s0[4*s+0]), "v"(s0[4*s+1]));
                asm("v_cvt_pk_bf16_f32 %0, %1, %2" : "=v"(D[s][1]) : "v"(s0[4*s+2]), "v"(s0[4*s+3]));
            }
#pragma unroll
            for (int u = 0; u < 2; u++) {
                asm volatile("v_permlane32_swap_b32 %0, %1" : "+v"(D[0][u]), "+v"(D[1][u]));
                asm volatile("v_permlane32_swap_b32 %0, %1" : "+v"(D[2][u]), "+v"(D[3][u]));
                pbw[0][u] = D[0][u]; pbw[0][u + 2] = D[1][u];
                pbw[1][u] = D[2][u]; pbw[1][u + 2] = D[3][u];
            }
#pragma unroll
            for (int s = 0; s < 4; s++) {
                asm("v_cvt_pk_bf16_f32 %0, %1, %2" : "=v"(D[s][0]) : "v"(s1[4*s+0]), "v"(s1[4*s+1]));
                asm("v_cvt_pk_bf16_f32 %0, %1, %2" : "=v"(D[s][1]) : "v"(s1[4*s+2]), "v"(s1[4*s+3]));
            }
#pragma unroll
            for (int u = 0; u < 2; u++) {
                asm volatile("v_permlane32_swap_b32 %0, %1" : "+v"(D[0][u]), "+v"(D[1][u]));
                asm volatile("v_permlane32_swap_b32 %0, %1" : "+v"(D[2][u]), "+v"(D[3][u]));
                pbw[2][u] = D[0][u]; pbw[2][u + 2] = D[1][u];
                pbw[3][u] = D[2][u]; pbw[3][u + 2] = D[3][u];
            }
#pragma unroll
            for (int c = 0; c < 4; c++) {
                uintx4 pw; pw[0] = pbw[c][0]; pw[1] = pbw[c][1]; pw[2] = pbw[c][2]; pw[3] = pbw[c][3];
                short8 pf = __builtin_bit_cast(short8, pw);
                OA0 = __builtin_amdgcn_mfma_f32_32x32x16_bf16(vf0[c], pf, OA0, 0, 0, 0);
                OA1 = __builtin_amdgcn_mfma_f32_32x32x16_bf16(vf1[c], pf, OA1, 0, 0, 0);
            }
        }

        // ================= Q-TILE B =================
#pragma unroll
        for (int t = 0; t < 16; t++) { s0[t] = 0.f; s1[t] = 0.f; }
#pragma unroll
        for (int c = 0; c < 4; c++) {
            s0 = __builtin_amdgcn_mfma_f32_32x32x16_bf16(kf0[c], qfB[c], s0, 0, 0, 0);
            s1 = __builtin_amdgcn_mfma_f32_32x32x16_bf16(kf1[c], qfB[c], s1, 0, 0, 0);
        }
        {   // kf dead: prefetch next K (pinned)
            const unsigned short* kn = kh + (size_t)tnx * 4096 + lo;
#pragma unroll
            for (int c = 0; c < 4; c++) {
                kf0[c] = *reinterpret_cast<const short8*>(kn + c * 1024);
                kf1[c] = *reinterpret_cast<const short8*>(kn + c * 1024 + 256);
            }
        }
        __builtin_amdgcn_sched_barrier(0);

        if (kt + 64 > vle) {
#pragma unroll
            for (int t = 0; t < 16; t++) {
                int kl = (t & 3) + 8 * (t >> 2) + 4 * hi;
                if (kt + kl >= vle)      s0[t] = -8.0e12f;
                if (kt + 32 + kl >= vle) s1[t] = -8.0e12f;
            }
        }
        {   // softmax B
            float mx = s0[0];
#pragma unroll
            for (int t = 1; t < 16; t++) mx = fmaxf(mx, s0[t]);
#pragma unroll
            for (int t = 0; t < 16; t++) mx = fmaxf(mx, s1[t]);
            float lm = fmaxf(mx, __shfl_xor(mx, 32));
            if (__any(lm > mB + 64.f)) {
                float mn = fmaxf(mB, lm);
                float al = __builtin_amdgcn_exp2f((mB - mn) * CEXP);
                mB = mn; lB *= al;
#pragma unroll
                for (int t = 0; t < 16; t++) { OB0[t] *= al; OB1[t] *= al; }
            }
            float nm = -mB * CEXP;
#pragma unroll
            for (int t = 0; t < 16; t++) {
                s0[t] = __builtin_amdgcn_exp2f(fmaf(s0[t], CEXP, nm));
                s1[t] = __builtin_amdgcn_exp2f(fmaf(s1[t], CEXP, nm));
            }
            float rs = 0.f;
#pragma unroll
            for (int t = 0; t < 16; t++) rs += s0[t] + s1[t];
            lB += rs;
        }
        {   // pack B + PV B
            unsigned int pbw[4][4];
            unsigned int D[4][2];
#pragma unroll
            for (int s = 0; s < 4; s++) {
                asm("v_cvt_pk_bf16_f32 %0, %1, %2" : "=v"(D[s][0]) : "v"(s0[4*s+0]), "v"(s0[4*s+1]));
                asm("v_cvt_pk_bf16_f32 %0, %1, %2" : "=v"(D[s][1]) : "v"(s0[4*s+2]), "v"(s0[4*s+3]));
            }
#pragma unroll
            for (int u = 0; u < 2; u++) {
                asm volatile("v_permlane32_swap_b32 %0, %1" : "+v"(D[0][u]), "+v"(D[1][u]));
                asm volatile("v_permlane32_swap_b32 %0, %1" : "+v"(D[2][u]), "+v"(D[3][u]));
                pbw[0][u] = D[0][u]; pbw[0][u + 2] = D[1][u];
                pbw[1][u] = D[2][u]; pbw[1][u + 2] = D[3][u];
            }
#pragma unroll
            for (int s = 0; s < 4; s++) {
                asm("v_cvt_pk_bf16_f32 %0, %1, %2" : "=v"(D[s][0]) : "v"(s1[4*s+0]), "v"(s1[4*s+1]));
                asm("v_cvt_pk_bf16_f32 %0, %1, %2" : "=v"(D[s][1]) : "v"(s1[4*s+2]), "v"(s1[4*s+3]));
            }
#pragma unroll
            for (int u = 0; u < 2; u++) {
                asm volatile("v_permlane32_swap_b32 %0, %1" : "+v"(D[0][u]), "+v"(D[1][u]));
                asm volatile("v_permlane32_swap_b32 %0, %1" : "+v"(D[2][u]), "+v"(D[3][u]));
                pbw[2][u] = D[0][u]; pbw[2][u + 2] = D[1][u];
                pbw[3][u] = D[2][u]; pbw[3][u + 2] = D[3][u];
            }
#pragma unroll
            for (int c = 0; c < 4; c++) {
                uintx4 pw; pw[0] = pbw[c][0]; pw[1] = pbw[c][1]; pw[2] = pbw[c][2]; pw[3] = pbw[c][3];
                short8 pf = __builtin_bit_cast(short8, pw);
                OB0 = __builtin_amdgcn_mfma_f32_32x32x16_bf16(vf0[c], pf, OB0, 0, 0, 0);
                OB1 = __builtin_amdgcn_mfma_f32_32x32x16_bf16(vf1[c], pf, OB1, 0, 0, 0);
            }
        }
        {   // vf dead: prefetch next V (pinned)
            const unsigned short* vn = vb + (size_t)tnx * 4096 + lo;
#pragma unroll
            for (int c = 0; c < 4; c++) {
                vf0[c] = *reinterpret_cast<const short8*>(vn + c * 1024);
                vf1[c] = *reinterpret_cast<const short8*>(vn + c * 1024 + 256);
            }
        }
        __builtin_amdgcn_sched_barrier(0);
    }

    // ================= combine (2 waves x 2 qtiles) ========================
    lA = lA + __shfl_xor(lA, 32);
    lB = lB + __shfl_xor(lB, 32);
    if (hi == 0) { mlm[0][w][j] = mA; mlm[1][w][j] = mB; }
    __syncthreads();
    float MA = fmaxf(mlm[0][0][j], mlm[0][1][j]);
    float MB = fmaxf(mlm[1][0][j], mlm[1][1][j]);
    float alA = __builtin_amdgcn_exp2f((mA - MA) * CEXP);
    float alB = __builtin_amdgcn_exp2f((mB - MB) * CEXP);
#pragma unroll
    for (int t = 0; t < 16; t++) { OA0[t] *= alA; OA1[t] *= alA; OB0[t] *= alB; OB1[t] *= alB; }
    if (hi == 0) { mll[0][w][j] = lA * alA; mll[1][w][j] = lB * alB; }
    if (w == 1) {
#pragma unroll
        for (int t = 0; t < 16; t++) {
            obuf[0][lane][t]      = OA0[t];
            obuf[0][lane][t + 16] = OA1[t];
            obuf[1][lane][t]      = OB0[t];
            obuf[1][lane][t + 16] = OB1[t];
        }
    }
    __syncthreads();
    if (w == 0) {
#pragma unroll
        for (int t = 0; t < 16; t++) {
            OA0[t] += obuf[0][lane][t];
            OA1[t] += obuf[0][lane][t + 16];
            OB0[t] += obuf[1][lane][t];
            OB1[t] += obuf[1][lane][t + 16];
        }
        float ltA = mll[0][0][j] + mll[0][1][j];
        float ltB = mll[1][0][j] + mll[1][1][j];
        int qrA = qb * 64 + j, qrB = qb * 64 + 32 + j;
        float qmA = (qrA < qlen) ? (1.0f / ltA) : 0.f;
        float qmB = (qrB < qlen) ? (1.0f / ltB) : 0.f;
        float* oa = out + (size_t)(b * 2048 + qrA) * 1024 + h * 64;
        float* ob = out + (size_t)(b * 2048 + qrB) * 1024 + h * 64;
#pragma unroll
        for (int s = 0; s < 4; s++) {
            float4 v0, v1;
            v0.x = OA0[4*s+0] * qmA; v0.y = OA0[4*s+1] * qmA; v0.z = OA0[4*s+2] * qmA; v0.w = OA0[4*s+3] * qmA;
            v1.x = OA1[4*s+0] * qmA; v1.y = OA1[4*s+1] * qmA; v1.z = OA1[4*s+2] * qmA; v1.w = OA1[4*s+3] * qmA;
            *reinterpret_cast<float4*>(oa + 8 * s + 4 * hi) = v0;
            *reinterpret_cast<float4*>(oa + 32 + 8 * s + 4 * hi) = v1;
            v0.x = OB0[4*s+0] * qmB; v0.y = OB0[4*s+1] * qmB; v0.z = OB0[4*s+2] * qmB; v0.w = OB0[4*s+3] * qmB;
            v1.x = OB1[4*s+0] * qmB; v1.y = OB1[4*s+1] * qmB; v1.z = OB1[4*s+2] * qmB; v1.w = OB1[4*s+3] * qmB;
            *reinterpret_cast<float4*>(ob + 8 * s + 4 * hi) = v0;
            *reinterpret_cast<float4*>(ob + 32 + 8 * s + 4 * hi) = v1;
        }
    }
}

// ---------------------------------------------------------------------------
extern "C" void kernel_launch(void* const* d_in, const int* in_sizes, int n_in,
                              void* d_out, int out_size, void* d_ws, size_t ws_size,
                              hipStream_t stream)
{
    const float* Q_seq = (const float*)d_in[0];
    const float* K_seq = (const float*)d_in[1];
    const float* V_seq = (const float*)d_in[2];
    const int*   Q_len = (const int*)d_in[3];
    const int*   V_len = (const int*)d_in[4];
    const float* WQ    = (const float*)d_in[5];
    const float* WK    = (const float*)d_in[6];
    const float* WV    = (const float*)d_in[7];
    float* outp = (float*)d_out;

    // ws layout (bf16 elems): wt[3*1M] | qh[4M] | kh[4M] | vh[4M] | abf[3*4M]
    unsigned short* wsb = (unsigned short*)d_ws;
    unsigned short* wt  = wsb;
    unsigned short* qp  = wsb + (size_t)3 * 1048576u;
    unsigned short* kp  = qp + 4194304u;
    unsigned short* vhp = kp + 4194304u;
    unsigned short* abf = vhp + 4194304u;

    wt_kernel<<<dim3(16, 16, 3), 256, 0, stream>>>(WQ, WK, WV, wt);
    cvt_kernel<<<dim3(4096, 3), 256, 0, stream>>>(Q_seq, K_seq, V_seq, Q_len, V_len, abf);
    proj_kernel<<<dim3(8, 32, 3), 256, 0, stream>>>(abf, wt, Q_len, V_len, qp, kp, vhp);
    attn_kernel<<<dim3(1024), 128, 0, stream>>>(qp, kp, vhp, Q_len, V_len, outp);
}

// Round 16
// 68.363 us; speedup vs baseline: 1.0428x; 1.0168x over previous
//
#include <hip/hip_runtime.h>

// MultiHeadAttn: B=2, T=2048, D=1024, H=16, dh=64
// R16 = R15/R11 pipeline + ILP-interleaved attn loop: QK^T(A)+QK^T(B) issued
// together, softmax(A) and softmax(B) back-to-back (independent serial VALU
// chains -> scheduler overlaps them), pack/PV phased to bound VGPR.
// Everything else identical to R15 (best reproduced config, 68-70us).

using short8   = __attribute__((ext_vector_type(8))) short;
using floatx4  = __attribute__((ext_vector_type(4))) float;
using floatx16 = __attribute__((ext_vector_type(16))) float;
using uintx4   = __attribute__((ext_vector_type(4))) unsigned int;
using ushort4v = __attribute__((ext_vector_type(4))) unsigned short;

__device__ __forceinline__ unsigned short f2bf(float f) {
    unsigned int u = __builtin_bit_cast(unsigned int, f);
    u += 0x7fffu + ((u >> 16) & 1u);
    return (unsigned short)(u >> 16);
}

// ---------------------------------------------------------------------------
// Kernel 0: fp32 -> bf16 convert of needed rows.
// ---------------------------------------------------------------------------
__global__ __launch_bounds__(256) void cvt_kernel(
    const float* __restrict__ Qs, const float* __restrict__ Ks,
    const float* __restrict__ Vs, const int* __restrict__ Qlen,
    const int* __restrict__ Vlen, unsigned short* __restrict__ abf)
{
    int z = blockIdx.y, row = blockIdx.x;
    int b = row >> 11, rib = row & 2047;
    int ql = Qlen[b]; int vl = Vlen[b]; int vle = vl ? vl : 2048;
    int lim = (z == 0) ? ((ql + 127) & ~127) : ((vle + 127) & ~127);
    if (rib >= lim) return;
    const float* src = (z == 0) ? Qs : ((z == 1) ? Ks : Vs);
    int t = threadIdx.x;
    float4 v = *reinterpret_cast<const float4*>(src + (size_t)row * 1024 + t * 4);
    ushort4v o;
    o[0] = f2bf(v.x); o[1] = f2bf(v.y); o[2] = f2bf(v.z); o[3] = f2bf(v.w);
    *reinterpret_cast<ushort4v*>(abf + (size_t)z * 4194304u + (size_t)row * 1024 + t * 4) = o;
}

// ---------------------------------------------------------------------------
// Kernel 1: W [1024][1024] f32 -> W^T [1024][1024] bf16 (z = 0,1,2)
// ---------------------------------------------------------------------------
__global__ __launch_bounds__(256) void wt_kernel(
    const float* __restrict__ W0, const float* __restrict__ W1,
    const float* __restrict__ W2, unsigned short* __restrict__ out)
{
    __shared__ float tile[64][65];
    int z = blockIdx.z;
    const float* W = (z == 0) ? W0 : ((z == 1) ? W1 : W2);
    unsigned short* O = out + (size_t)z * 1048576u;
    int r0 = blockIdx.y * 64, c0 = blockIdx.x * 64;
    int t = threadIdx.x;
#pragma unroll
    for (int i = 0; i < 16; i++) {
        int idx = t + i * 256; int r = idx >> 6, c = idx & 63;
        tile[r][c] = W[(size_t)(r0 + r) * 1024 + c0 + c];
    }
    __syncthreads();
#pragma unroll
    for (int i = 0; i < 16; i++) {
        int idx = t + i * 256; int c = idx >> 6, r = idx & 63;
        O[(size_t)(c0 + c) * 1024 + r0 + r] = f2bf(tile[r][c]);
    }
}

// ---------------------------------------------------------------------------
// Kernel 2: projection GEMM (PRECVT); permuted per-head tile epilogue.
// ---------------------------------------------------------------------------
__global__ __launch_bounds__(256) void proj_kernel(
    const unsigned short* __restrict__ abf, const unsigned short* __restrict__ wt,
    const int* __restrict__ Qlen, const int* __restrict__ Vlen,
    unsigned short* __restrict__ q, unsigned short* __restrict__ k,
    unsigned short* __restrict__ vh)
{
    __shared__ alignas(16) unsigned short As[128][72];
    __shared__ alignas(16) unsigned short Bs[128][72];

    int z = blockIdx.z;
    int tid = threadIdx.x;
    int m0 = blockIdx.y * 128, n0 = blockIdx.x * 128;
    int b = m0 >> 11, rib = m0 & 2047;
    int ql = Qlen[b]; int vl = Vlen[b]; int vle = vl ? vl : 2048;
    int lim = (z == 0) ? ((ql + 127) & ~127) : ((vle + 127) & ~127);
    if (rib >= lim) return;

    const unsigned short* Ab = abf + (size_t)z * 4194304u;
    const unsigned short* Bt = wt + (size_t)z * 1048576u;

    int w = tid >> 6, lane = tid & 63, g = lane >> 4, lr = lane & 15;
    int wr = w >> 1, wc = w & 1;

    floatx4 acc[4][4];
#pragma unroll
    for (int m = 0; m < 4; m++)
#pragma unroll
        for (int n = 0; n < 4; n++) {
#pragma unroll
            for (int r = 0; r < 4; r++) acc[m][n][r] = 0.f;
        }

    int srow = tid >> 1, scol = (tid & 1) * 32;

    short8 pa[4], pb[4];
#pragma unroll
    for (int i = 0; i < 4; i++) {
        pa[i] = *reinterpret_cast<const short8*>(Ab + (size_t)(m0 + srow) * 1024 + scol + i * 8);
        pb[i] = *reinterpret_cast<const short8*>(Bt + (size_t)(n0 + srow) * 1024 + scol + i * 8);
    }

    for (int kb = 0; kb < 1024; kb += 64) {
        __syncthreads();
#pragma unroll
        for (int i = 0; i < 4; i++) {
            *reinterpret_cast<short8*>(&As[srow][scol + i * 8]) = pa[i];
            *reinterpret_cast<short8*>(&Bs[srow][scol + i * 8]) = pb[i];
        }
        __syncthreads();

        if (kb + 64 < 1024) {
#pragma unroll
            for (int i = 0; i < 4; i++) {
                pa[i] = *reinterpret_cast<const short8*>(Ab + (size_t)(m0 + srow) * 1024 + kb + 64 + scol + i * 8);
                pb[i] = *reinterpret_cast<const short8*>(Bt + (size_t)(n0 + srow) * 1024 + kb + 64 + scol + i * 8);
            }
        }

#pragma unroll
        for (int kc = 0; kc < 2; kc++) {
            short8 af[4], bf[4];
#pragma unroll
            for (int m = 0; m < 4; m++)
                af[m] = *reinterpret_cast<const short8*>(&As[wr * 64 + m * 16 + lr][kc * 32 + g * 8]);
#pragma unroll
            for (int n = 0; n < 4; n++)
                bf[n] = *reinterpret_cast<const short8*>(&Bs[wc * 64 + n * 16 + lr][kc * 32 + g * 8]);
#pragma unroll
            for (int m = 0; m < 4; m++)
#pragma unroll
                for (int n = 0; n < 4; n++)
                    acc[m][n] = __builtin_amdgcn_mfma_f32_16x16x32_bf16(af[m], bf[n], acc[m][n], 0, 0, 0);
        }
    }

    if (z < 2) {
        unsigned short* outp = (z == 0) ? q : k;
#pragma unroll
        for (int m = 0; m < 4; m++) {
            int row0 = m0 + wr * 64 + m * 16 + g * 4;
            int tb = row0 & 2047;
            int tile = tb >> 6, rin = tb & 63;
#pragma unroll
            for (int n = 0; n < 4; n++) {
                int col = n0 + wc * 64 + n * 16 + lr;
                int hh = col >> 6, dd = col & 63;
                int cc = dd >> 4, h2 = (dd >> 3) & 1, u = dd & 7;
                size_t base = ((size_t)(b * 16 + hh) * 32 + tile) * 4096
                            + (size_t)((cc * 2 + h2) * 512) + (size_t)rin * 8 + u;
#pragma unroll
                for (int r = 0; r < 4; r++)
                    outp[base + (size_t)r * 8] = f2bf(acc[m][n][r]);
            }
        }
    } else {
#pragma unroll
        for (int m = 0; m < 4; m++) {
            int row0 = m0 + wr * 64 + m * 16 + g * 4;
            int tg = row0 & 2047;
            int tile = tg >> 6, kin = tg & 63;
            int cc = kin >> 4, h2 = (kin >> 3) & 1, u = kin & 7;
#pragma unroll
            for (int n = 0; n < 4; n++) {
                int col = n0 + wc * 64 + n * 16 + lr;
                int hh = col >> 6, dd = col & 63;
                ushort4v pk;
#pragma unroll
                for (int r = 0; r < 4; r++) pk[r] = f2bf(acc[m][n][r]);
                size_t addr = ((size_t)(b * 16 + hh) * 32 + tile) * 4096
                            + (size_t)((cc * 2 + h2) * 512) + (size_t)dd * 8 + u;
                *reinterpret_cast<ushort4v*>(vh + addr) = pk;
            }
        }
    }
}

// ---------------------------------------------------------------------------
// Kernel 3: flash attention. R15 structure with interleaved A/B phases:
// QK^T(A)+QK^T(B) issued together; softmax(A);softmax(B) adjacent so the
// scheduler overlaps the two independent serial chains; pack+PV phased.
// ---------------------------------------------------------------------------
__global__ __launch_bounds__(128) void attn_kernel(
    const unsigned short* __restrict__ q, const unsigned short* __restrict__ k,
    const unsigned short* __restrict__ vh, const int* __restrict__ Qlen,
    const int* __restrict__ Vlen, float* __restrict__ out)
{
    __shared__ float obuf[2][64][33];
    __shared__ float mlm[2][2][33];
    __shared__ float mll[2][2][33];

    int tid = threadIdx.x;
    int w = tid >> 6, lane = tid & 63;
    int j = lane & 31, hi = lane >> 5;

    int blk = blockIdx.x;
    int x = blk & 7, idx = blk >> 3;
    int bh = x + 8 * (idx >> 5), qb = idx & 31;
    int b = bh >> 4, h = bh & 15;
    int qlen = Qlen[b]; int vl = Vlen[b]; int vle = vl ? vl : 2048;

    if (qb * 64 >= qlen) {   // dead block -> zeros
        int zr = qb * 64 + (tid >> 1);
        float* p = out + (size_t)(b * 2048 + zr) * 1024 + h * 64 + (tid & 1) * 32;
        float4 z4; z4.x = 0.f; z4.y = 0.f; z4.z = 0.f; z4.w = 0.f;
#pragma unroll
        for (int s = 0; s < 8; s++) *reinterpret_cast<float4*>(p + 4 * s) = z4;
        return;
    }

    int nt = (vle + 63) >> 6;
    int ntw = (nt - w + 1) >> 1;

    size_t hb = (size_t)(b * 16 + h) * 131072u;
    const unsigned short* kh = k + hb;
    const unsigned short* vb = vh + hb;
    int lo = hi * 512 + j * 8;

    short8 qfA[4], qfB[4];
    {
        const unsigned short* qt = q + hb + (size_t)qb * 4096 + lo;
#pragma unroll
        for (int c = 0; c < 4; c++) {
            qfA[c] = *reinterpret_cast<const short8*>(qt + c * 1024);
            qfB[c] = *reinterpret_cast<const short8*>(qt + c * 1024 + 256);
        }
    }

    short8 kf0[4], kf1[4], vf0[4], vf1[4];
    {
        int t0 = (w < nt) ? w : (nt - 1);
        const unsigned short* kt0 = kh + (size_t)t0 * 4096 + lo;
        const unsigned short* vt0 = vb + (size_t)t0 * 4096 + lo;
#pragma unroll
        for (int c = 0; c < 4; c++) {
            kf0[c] = *reinterpret_cast<const short8*>(kt0 + c * 1024);
            kf1[c] = *reinterpret_cast<const short8*>(kt0 + c * 1024 + 256);
            vf0[c] = *reinterpret_cast<const short8*>(vt0 + c * 1024);
            vf1[c] = *reinterpret_cast<const short8*>(vt0 + c * 1024 + 256);
        }
    }
    __builtin_amdgcn_sched_barrier(0);

    floatx16 OA0, OA1, OB0, OB1;
#pragma unroll
    for (int t = 0; t < 16; t++) { OA0[t] = 0.f; OA1[t] = 0.f; OB0[t] = 0.f; OB1[t] = 0.f; }
    float mA = -3.0e38f, lA = 0.f, mB = -3.0e38f, lB = 0.f;

    const float CEXP = 0.18033688011112042f;

    for (int mi = 0; mi < ntw; ++mi) {
        int tix = w + 2 * mi;
        int kt = tix << 6;
        int tnx = tix + 2; if (tnx >= nt) tnx = nt - 1;

        // ---- QK^T for BOTH q-tiles (16 independent MFMAs)
        floatx16 sA0, sA1, sB0, sB1;
#pragma unroll
        for (int t = 0; t < 16; t++) { sA0[t] = 0.f; sA1[t] = 0.f; sB0[t] = 0.f; sB1[t] = 0.f; }
#pragma unroll
        for (int c = 0; c < 4; c++) {
            sA0 = __builtin_amdgcn_mfma_f32_32x32x16_bf16(kf0[c], qfA[c], sA0, 0, 0, 0);
            sB0 = __builtin_amdgcn_mfma_f32_32x32x16_bf16(kf0[c], qfB[c], sB0, 0, 0, 0);
            sA1 = __builtin_amdgcn_mfma_f32_32x32x16_bf16(kf1[c], qfA[c], sA1, 0, 0, 0);
            sB1 = __builtin_amdgcn_mfma_f32_32x32x16_bf16(kf1[c], qfB[c], sB1, 0, 0, 0);
        }

        // ---- kf dead: prefetch next K NOW (flies under softmax+pack+PV)
        {
            const unsigned short* kn = kh + (size_t)tnx * 4096 + lo;
#pragma unroll
            for (int c = 0; c < 4; c++) {
                kf0[c] = *reinterpret_cast<const short8*>(kn + c * 1024);
                kf1[c] = *reinterpret_cast<const short8*>(kn + c * 1024 + 256);
            }
        }
        __builtin_amdgcn_sched_barrier(0);

        if (kt + 64 > vle) {   // boundary masking, both tiles
#pragma unroll
            for (int t = 0; t < 16; t++) {
                int kl = (t & 3) + 8 * (t >> 2) + 4 * hi;
                if (kt + kl >= vle)      { sA0[t] = -8.0e12f; sB0[t] = -8.0e12f; }
                if (kt + 32 + kl >= vle) { sA1[t] = -8.0e12f; sB1[t] = -8.0e12f; }
            }
        }

        // ---- softmax A and B adjacent (independent chains -> overlapped)
        {
            float mxA = sA0[0], mxB = sB0[0];
#pragma unroll
            for (int t = 1; t < 16; t++) { mxA = fmaxf(mxA, sA0[t]); mxB = fmaxf(mxB, sB0[t]); }
#pragma unroll
            for (int t = 0; t < 16; t++) { mxA = fmaxf(mxA, sA1[t]); mxB = fmaxf(mxB, sB1[t]); }
            float lmA = fmaxf(mxA, __shfl_xor(mxA, 32));
            float lmB = fmaxf(mxB, __shfl_xor(mxB, 32));
            if (__any(lmA > mA + 64.f)) {
                float mn = fmaxf(mA, lmA);
                float al = __builtin_amdgcn_exp2f((mA - mn) * CEXP);
                mA = mn; lA *= al;
#pragma unroll
                for (int t = 0; t < 16; t++) { OA0[t] *= al; OA1[t] *= al; }
            }
            if (__any(lmB > mB + 64.f)) {
                float mn = fmaxf(mB, lmB);
                float al = __builtin_amdgcn_exp2f((mB - mn) * CEXP);
                mB = mn; lB *= al;
#pragma unroll
                for (int t = 0; t < 16; t++) { OB0[t] *= al; OB1[t] *= al; }
            }
            float nmA = -mA * CEXP, nmB = -mB * CEXP;
#pragma unroll
            for (int t = 0; t < 16; t++) {
                sA0[t] = __builtin_amdgcn_exp2f(fmaf(sA0[t], CEXP, nmA));
                sB0[t] = __builtin_amdgcn_exp2f(fmaf(sB0[t], CEXP, nmB));
                sA1[t] = __builtin_amdgcn_exp2f(fmaf(sA1[t], CEXP, nmA));
                sB1[t] = __builtin_amdgcn_exp2f(fmaf(sB1[t], CEXP, nmB));
            }
            float rsA = 0.f, rsB = 0.f;
#pragma unroll
            for (int t = 0; t < 16; t++) { rsA += sA0[t] + sA1[t]; rsB += sB0[t] + sB1[t]; }
            lA += rsA; lB += rsB;
        }

        // ---- pack A + PV A
        {
            unsigned int pbw[4][4];
            unsigned int D[4][2];
#pragma unroll
            for (int s = 0; s < 4; s++) {
                asm("v_cvt_pk_bf16_f32 %0, %1, %2" : "=v"(D[s][0]) : "v"(sA0[4*s+0]), "v"(sA0[4*s+1]));
                asm("v_cvt_pk_bf16_f32 %0, %1, %2" : "=v"(D[s][1]) : "v"(sA0[4*s+2]), "v"(sA0[4*s+3]));
            }
#pragma unroll
            for (int u = 0; u < 2; u++) {
                asm volatile("v_permlane32_swap_b32 %0, %1" : "+v"(D[0][u]), "+v"(D[1][u]));
                asm volatile("v_permlane32_swap_b32 %0, %1" : "+v"(D[2][u]), "+v"(D[3][u]));
                pbw[0][u] = D[0][u]; pbw[0][u + 2] = D[1][u];
                pbw[1][u] = D[2][u]; pbw[1][u + 2] = D[3][u];
            }
#pragma unroll
            for (int s = 0; s < 4; s++) {
                asm("v_cvt_pk_bf16_f32 %0, %1, %2" : "=v"(D[s][0]) : "v"(sA1[4*s+0]), "v"(sA1[4*s+1]));
                asm("v_cvt_pk_bf16_f32 %0, %1, %2" : "=v"(D[s][1]) : "v"(sA1[4*s+2]), "v"(sA1[4*s+3]));
            }
#pragma unroll
            for (int u = 0; u < 2; u++) {
                asm volatile("v_permlane32_swap_b32 %0, %1" : "+v"(D[0][u]), "+v"(D[1][u]));
                asm volatile("v_permlane32_swap_b32 %0, %1" : "+v"(D[2][u]), "+v"(D[3][u]));
                pbw[2][u] = D[0][u]; pbw[2][u + 2] = D[1][u];
                pbw[3][u] = D[2][u]; pbw[3][u + 2] = D[3][u];
            }
#pragma unroll
            for (int c = 0; c < 4; c++) {
                uintx4 pw; pw[0] = pbw[c][0]; pw[1] = pbw[c][1]; pw[2] = pbw[c][2]; pw[3] = pbw[c][3];
                short8 pf = __builtin_bit_cast(short8, pw);
                OA0 = __builtin_amdgcn_mfma_f32_32x32x16_bf16(vf0[c], pf, OA0, 0, 0, 0);
                OA1 = __builtin_amdgcn_mfma_f32_32x32x16_bf16(vf1[c], pf, OA1, 0, 0, 0);
            }
        }

        // ---- pack B + PV B
        {
            unsigned int pbw[4][4];
            unsigned int D[4][2];
#pragma unroll
            for (int s = 0; s < 4; s++) {
                asm("v_cvt_pk_bf16_f32 %0, %1, %2" : "=v"(D[s][0]) : "v"(sB0[4*s+0]), "v"(sB0[4*s+1]));
                asm("v_cvt_pk_bf16_f32 %0, %1, %2" : "=v"(D[s][1]) : "v"(sB0[4*s+2]), "v"(sB0[4*s+3]));
            }
#pragma unroll
            for (int u = 0; u < 2; u++) {
                asm volatile("v_permlane32_swap_b32 %0, %1" : "+v"(D[0][u]), "+v"(D[1][u]));
                asm volatile("v_permlane32_swap_b32 %0, %1" : "+v"(D[2][u]), "+v"(D[3][u]));
                pbw[0][u] = D[0][u]; pbw[0][u + 2] = D[1][u];
                pbw[1][u] = D[2][u]; pbw[1][u + 2] = D[3][u];
            }
#pragma unroll
            for (int s = 0; s < 4; s++) {
                asm("v_cvt_pk_bf16_f32 %0, %1, %2" : "=v"(D[s][0]) : "v"(sB1[4*s+0]), "v"(sB1[4*s+1]));
                asm("v_cvt_pk_bf16_f32 %0, %1, %2" : "=v"(D[s][1]) : "v"(sB1[4*s+2]), "v"(sB1[4*s+3]));
            }
#pragma unroll
            for (int u = 0; u < 2; u++) {
                asm volatile("v_permlane32_swap_b32 %0, %1" : "+v"(D[0][u]), "+v"(D[1][u]));
                asm volatile("v_permlane32_swap_b32 %0, %1" : "+v"(D[2][u]), "+v"(D[3][u]));
                pbw[2][u] = D[0][u]; pbw[2][u + 2] = D[1][u];
                pbw[3][u] = D[2][u]; pbw[3][u + 2] = D[3][u];
            }
#pragma unroll
            for (int c = 0; c < 4; c++) {
                uintx4 pw; pw[0] = pbw[c][0]; pw[1] = pbw[c][1]; pw[2] = pbw[c][2]; pw[3] = pbw[c][3];
                short8 pf = __builtin_bit_cast(short8, pw);
                OB0 = __builtin_amdgcn_mfma_f32_32x32x16_bf16(vf0[c], pf, OB0, 0, 0, 0);
                OB1 = __builtin_amdgcn_mfma_f32_32x32x16_bf16(vf1[c], pf, OB1, 0, 0, 0);
            }
        }

        // ---- vf dead: prefetch next V (pinned)
        {
            const unsigned short* vn = vb + (size_t)tnx * 4096 + lo;
#pragma unroll
            for (int c = 0; c < 4; c++) {
                vf0[c] = *reinterpret_cast<const short8*>(vn + c * 1024);
                vf1[c] = *reinterpret_cast<const short8*>(vn + c * 1024 + 256);
            }
        }
        __builtin_amdgcn_sched_barrier(0);
    }

    // ================= combine (2 waves x 2 qtiles) ========================
    lA = lA + __shfl_xor(lA, 32);
    lB = lB + __shfl_xor(lB, 32);
    if (hi == 0) { mlm[0][w][j] = mA; mlm[1][w][j] = mB; }
    __syncthreads();
    float MA = fmaxf(mlm[0][0][j], mlm[0][1][j]);
    float MB = fmaxf(mlm[1][0][j], mlm[1][1][j]);
    float alA = __builtin_amdgcn_exp2f((mA - MA) * CEXP);
    float alB = __builtin_amdgcn_exp2f((mB - MB) * CEXP);
#pragma unroll
    for (int t = 0; t < 16; t++) { OA0[t] *= alA; OA1[t] *= alA; OB0[t] *= alB; OB1[t] *= alB; }
    if (hi == 0) { mll[0][w][j] = lA * alA; mll[1][w][j] = lB * alB; }
    if (w == 1) {
#pragma unroll
        for (int t = 0; t < 16; t++) {
            obuf[0][lane][t]      = OA0[t];
            obuf[0][lane][t + 16] = OA1[t];
            obuf[1][lane][t]      = OB0[t];
            obuf[1][lane][t + 16] = OB1[t];
        }
    }
    __syncthreads();
    if (w == 0) {
#pragma unroll
        for (int t = 0; t < 16; t++) {
            OA0[t] += obuf[0][lane][t];
            OA1[t] += obuf[0][lane][t + 16];
            OB0[t] += obuf[1][lane][t];
            OB1[t] += obuf[1][lane][t + 16];
        }
        float ltA = mll[0][0][j] + mll[0][1][j];
        float ltB = mll[1][0][j] + mll[1][1][j];
        int qrA = qb * 64 + j, qrB = qb * 64 + 32 + j;
        float qmA = (qrA < qlen) ? (1.0f / ltA) : 0.f;
        float qmB = (qrB < qlen) ? (1.0f / ltB) : 0.f;
        float* oa = out + (size_t)(b * 2048 + qrA) * 1024 + h * 64;
        float* ob = out + (size_t)(b * 2048 + qrB) * 1024 + h * 64;
#pragma unroll
        for (int s = 0; s < 4; s++) {
            float4 v0, v1;
            v0.x = OA0[4*s+0] * qmA; v0.y = OA0[4*s+1] * qmA; v0.z = OA0[4*s+2] * qmA; v0.w = OA0[4*s+3] * qmA;
            v1.x = OA1[4*s+0] * qmA; v1.y = OA1[4*s+1] * qmA; v1.z = OA1[4*s+2] * qmA; v1.w = OA1[4*s+3] * qmA;
            *reinterpret_cast<float4*>(oa + 8 * s + 4 * hi) = v0;
            *reinterpret_cast<float4*>(oa + 32 + 8 * s + 4 * hi) = v1;
            v0.x = OB0[4*s+0] * qmB; v0.y = OB0[4*s+1] * qmB; v0.z = OB0[4*s+2] * qmB; v0.w = OB0[4*s+3] * qmB;
            v1.x = OB1[4*s+0] * qmB; v1.y = OB1[4*s+1] * qmB; v1.z = OB1[4*s+2] * qmB; v1.w = OB1[4*s+3] * qmB;
            *reinterpret_cast<float4*>(ob + 8 * s + 4 * hi) = v0;
            *reinterpret_cast<float4*>(ob + 32 + 8 * s + 4 * hi) = v1;
        }
    }
}

// ---------------------------------------------------------------------------
extern "C" void kernel_launch(void* const* d_in, const int* in_sizes, int n_in,
                              void* d_out, int out_size, void* d_ws, size_t ws_size,
                              hipStream_t stream)
{
    const float* Q_seq = (const float*)d_in[0];
    const float* K_seq = (const float*)d_in[1];
    const float* V_seq = (const float*)d_in[2];
    const int*   Q_len = (const int*)d_in[3];
    const int*   V_len = (const int*)d_in[4];
    const float* WQ    = (const float*)d_in[5];
    const float* WK    = (const float*)d_in[6];
    const float* WV    = (const float*)d_in[7];
    float* outp = (float*)d_out;

    // ws layout (bf16 elems): wt[3*1M] | qh[4M] | kh[4M] | vh[4M] | abf[3*4M]
    unsigned short* wsb = (unsigned short*)d_ws;
    unsigned short* wt  = wsb;
    unsigned short* qp  = wsb + (size_t)3 * 1048576u;
    unsigned short* kp  = qp + 4194304u;
    unsigned short* vhp = kp + 4194304u;
    unsigned short* abf = vhp + 4194304u;

    wt_kernel<<<dim3(16, 16, 3), 256, 0, stream>>>(WQ, WK, WV, wt);
    cvt_kernel<<<dim3(4096, 3), 256, 0, stream>>>(Q_seq, K_seq, V_seq, Q_len, V_len, abf);
    proj_kernel<<<dim3(8, 32, 3), 256, 0, stream>>>(abf, wt, Q_len, V_len, qp, kp, vhp);
    attn_kernel<<<dim3(1024), 128, 0, stream>>>(qp, kp, vhp, Q_len, V_len, outp);
}